// Round 6
// baseline (27388.562 us; speedup 1.0000x reference)
//
#include <hip/hip_runtime.h>
#include <hip/hip_bf16.h>

// MultilayerGRU: B=128, S=512, H=1024, L=2, O=1024
// Round 6: fence-free coherent scan (no XCD assumptions, no relay).
//  - cross-phase panels (h0 x2, h1 x2, rh0, rh1) written sc0sc1 (LLC),
//    read via __hip_atomic_load(u64, RELAXED, AGENT) = sc0sc1 dwordx2 loads
//    (compiler-scheduled -> full memory-level parallelism, no stale caches)
//  - no acquire fence / no buffer_inv anywhere in the loop
//  - flattened grid barrier: 8 arrival lines, pollers sum all 8
//  - roles: L0 (64 WG, zr@A/g@B), L1zg (128 WG, z@A/g@B, M-half),
//           L1r+OUT (64 WG, r@A / y-projection@B)

typedef __bf16 bf16;
typedef __attribute__((ext_vector_type(8))) __bf16 bf16x8;
typedef __attribute__((ext_vector_type(4))) __bf16 bf16x4;
typedef __attribute__((ext_vector_type(4))) float f32x4;

#define MFMA16(a, b, c) __builtin_amdgcn_mfma_f32_16x16x32_bf16(a, b, c, 0, 0, 0)

static __device__ __forceinline__ bf16x8 ldfrag(const bf16* p) {
  return *reinterpret_cast<const bf16x8*>(p);
}
static __device__ __forceinline__ float sigmf(float x) { return 1.f / (1.f + __expf(-x)); }

// write-through store: lands at the device coherence point (LLC), L2 stays clean
static __device__ __forceinline__ void st2_llc(bf16* p, bf16 v) {
  unsigned u = (unsigned)__builtin_bit_cast(unsigned short, v);
  asm volatile("global_store_short %0, %1, off sc0 sc1" :: "v"(p), "v"(u) : "memory");
}

// coherent 16B fragment load from LLC (two 8B relaxed agent-scope atomic loads;
// compiler emits global_load_dwordx2 sc0 sc1 and tracks vmcnt -> pipelined)
static __device__ __forceinline__ bf16x8 ldA_sc(const bf16* p) {
  union { unsigned long long q[2]; bf16x8 v; } u;
  u.q[0] = __hip_atomic_load((const unsigned long long*)p, __ATOMIC_RELAXED,
                             __HIP_MEMORY_SCOPE_AGENT);
  u.q[1] = __hip_atomic_load(((const unsigned long long*)p) + 1, __ATOMIC_RELAXED,
                             __HIP_MEMORY_SCOPE_AGENT);
  return u.v;
}
// coherent scalar bf16 load (via containing aligned 4B word)
static __device__ __forceinline__ float ldh_sc(const bf16* p) {
  const unsigned* a = (const unsigned*)((size_t)p & ~(size_t)3);
  unsigned v = __hip_atomic_load(a, __ATOMIC_RELAXED, __HIP_MEMORY_SCOPE_AGENT);
  unsigned short h = ((size_t)p & 2) ? (unsigned short)(v >> 16) : (unsigned short)(v & 0xffffu);
  return (float)__builtin_bit_cast(bf16, h);
}

// ---------------- weight cast (layer-0 Wx only, for gx0 GEMM) ----------------
__global__ void k_cast4(const float* __restrict__ s, bf16* __restrict__ d, int n4) {
  int i = blockIdx.x * blockDim.x + threadIdx.x;
  int st = gridDim.x * blockDim.x;
  for (; i < n4; i += st) {
    float4 v = reinterpret_cast<const float4*>(s)[i];
    bf16x4 o = {(bf16)v.x, (bf16)v.y, (bf16)v.z, (bf16)v.w};
    *reinterpret_cast<bf16x4*>(d + (size_t)i * 4) = o;
  }
}

// ---------------- gx0T[s][col][b] = (x @ Wx0^T + bh0) transposed ----------------
__global__ __launch_bounds__(256) void k_gx0T(const float* __restrict__ x,
                                              const bf16* __restrict__ wx0,
                                              const float* __restrict__ bh,
                                              bf16* __restrict__ gx0T) {
  const int lane = threadIdx.x & 63;
  const int gw = blockIdx.x * 4 + (threadIdx.x >> 6);
  const int NT = 3072 / 64;  // 48
  const int tm = gw / NT, tn = gw % NT;
  const int m0 = tm * 64, n0 = tn * 64;
  const int r = lane & 15, kq = lane >> 4;
  f32x4 acc[4][4] = {};
  for (int k0 = 0; k0 < 1024; k0 += 32) {
    const int k = k0 + kq * 8;
    bf16x8 a[4], b[4];
#pragma unroll
    for (int mi = 0; mi < 4; ++mi) {
      const int m = m0 + mi * 16 + r;
      const int bb = m & 127, s = m >> 7;
      const float* xp = x + ((size_t)(bb * 512 + s)) * 1024 + k;
      float4 lo = *reinterpret_cast<const float4*>(xp);
      float4 hi = *reinterpret_cast<const float4*>(xp + 4);
      bf16x8 av;
      av[0] = (bf16)lo.x; av[1] = (bf16)lo.y; av[2] = (bf16)lo.z; av[3] = (bf16)lo.w;
      av[4] = (bf16)hi.x; av[5] = (bf16)hi.y; av[6] = (bf16)hi.z; av[7] = (bf16)hi.w;
      a[mi] = av;
    }
#pragma unroll
    for (int ni = 0; ni < 4; ++ni)
      b[ni] = ldfrag(wx0 + (size_t)(n0 + ni * 16 + r) * 1024 + k);
#pragma unroll
    for (int mi = 0; mi < 4; ++mi)
#pragma unroll
      for (int ni = 0; ni < 4; ++ni) acc[mi][ni] = MFMA16(a[mi], b[ni], acc[mi][ni]);
  }
#pragma unroll
  for (int mi = 0; mi < 4; ++mi) {
#pragma unroll
    for (int ni = 0; ni < 4; ++ni) {
      const int col = n0 + ni * 16 + r;
      const float bias = bh[col];
      bf16x4 v;
#pragma unroll
      for (int j = 0; j < 4; ++j) v[j] = (bf16)(acc[mi][ni][j] + bias);
      const int m = m0 + mi * 16 + kq * 4;  // 4 consecutive b's (same s)
      const int s = m >> 7, bb = m & 127;
      *reinterpret_cast<bf16x4*>(gx0T + ((size_t)s * 3072 + col) * 128 + bb) = v;
    }
  }
}

// ---------------- persistent GRU scan ----------------
struct GP {
  const float* Wx;
  const float* Wh;
  const float* bh;
  const float* by;
  const float* Why;
  const bf16* gx0T;
  bf16* h0a;   // h0 parity buffers
  bf16* h0b;
  bf16* h1a;   // h1 parity buffers
  bf16* h1b;
  bf16* rh0M;
  bf16* rh1M;
  float* out;
  int* bar;
};

// flattened grid barrier: 8 arrival lines, poll sums all 8
__device__ __forceinline__ void gbar(int* bar, int gen) {
  asm volatile("s_waitcnt vmcnt(0)" ::: "memory");
  __syncthreads();
  if (threadIdx.x == 0) {
    atomicAdd(bar + (blockIdx.x & 7) * 32, 1);
    const int want = (gen + 1) * 256;
    for (;;) {
      int sum = 0;
#pragma unroll
      for (int g = 0; g < 8; ++g)
        sum += __hip_atomic_load(bar + g * 32, __ATOMIC_RELAXED, __HIP_MEMORY_SCOPE_AGENT);
      if (sum >= want) break;
      __builtin_amdgcn_s_sleep(1);
    }
  }
  __syncthreads();
}

__device__ __forceinline__ void stage_row8(char* dst, int row, int rb, int k8,
                                           const float* __restrict__ src) {
  const float4 f0 = *reinterpret_cast<const float4*>(src);
  const float4 f1 = *reinterpret_cast<const float4*>(src + 4);
  bf16x8 v;
  v[0] = (bf16)f0.x; v[1] = (bf16)f0.y; v[2] = (bf16)f0.z; v[3] = (bf16)f0.w;
  v[4] = (bf16)f1.x; v[5] = (bf16)f1.y; v[6] = (bf16)f1.z; v[7] = (bf16)f1.w;
  *reinterpret_cast<bf16x8*>(dst + (size_t)row * rb + ((k8 * 2) ^ ((row & 7) << 4))) = v;
}

// A from LLC (coherent), B from LDS
template <int MT, int NT, int RB>
__device__ __forceinline__ void mmA(const bf16* __restrict__ A, const char* __restrict__ ldsb,
                                    const int kloff, f32x4 (&acc)[MT][NT], const int m0,
                                    const int r, const int kq) {
#pragma unroll 8
  for (int k0 = 0; k0 < 1024; k0 += 32) {
    const int k = k0 + kq * 8;
    bf16x8 a[MT];
#pragma unroll
    for (int mi = 0; mi < MT; ++mi)
      a[mi] = ldA_sc(A + (size_t)(m0 + mi * 16 + r) * 1024 + k);
#pragma unroll
    for (int nt = 0; nt < NT; ++nt) {
      const bf16x8 b = *reinterpret_cast<const bf16x8*>(
          ldsb + (size_t)(nt * 16 + r) * RB + (((kloff + k) * 2) ^ ((r & 7) << 4)));
#pragma unroll
      for (int mi = 0; mi < MT; ++mi) acc[mi][nt] = MFMA16(a[mi], b, acc[mi][nt]);
    }
  }
}

__global__ void __launch_bounds__(256, 1) k_gru(GP P) {
  extern __shared__ char lds[];
  const int w = blockIdx.x;
  const int tid = threadIdx.x;
  const int r = tid & 15, kq = (tid >> 4) & 3, wv = tid >> 6;

  // ---- role geometry ----
  // w in [0,64):    L0   : c0=w*16        zr@A (LDS 0, 32x2KB), g@B (LDS 64K, 16x2KB)
  // w in [64,192):  L1zg : c0=((w-64)>>1)*16, mh=(w-64)&1 ; z@A / g@B (16x4KB each), M-half
  // w in [192,256): L1r  : c0=(w-192)*16  r@A (16x4KB), OUT@B (Why 16x2KB)
  int c0, mh = 0, role;
  if (w < 64) { role = 0; c0 = w * 16; }
  else if (w < 192) { role = 1; c0 = ((w - 64) >> 1) * 16; mh = (w - 64) & 1; }
  else { role = 2; c0 = (w - 192) * 16; }

  // ---- stage weights into LDS (once, f32 -> bf16, XOR-swizzled) ----
  if (role == 0) {
    for (int ch = tid; ch < 32 * 128; ch += 256) {  // rows 0-15 z, 16-31 r, K=1024
      const int row = ch >> 7, k8 = (ch & 127) * 8;
      const int gate = row >> 4, col = c0 + (row & 15);
      stage_row8(lds, row, 2048, k8, P.Wh + ((size_t)(gate * 1024 + col)) * 1024 + k8);
    }
    for (int ch = tid; ch < 16 * 128; ch += 256) {  // g
      const int row = ch >> 7, k8 = (ch & 127) * 8;
      stage_row8(lds + 65536, row, 2048, k8,
                 P.Wh + ((size_t)(2 * 1024 + c0 + row)) * 1024 + k8);
    }
  } else if (role == 1) {
    for (int ch = tid; ch < 16 * 256; ch += 256) {  // z, K=2048 concat [Wx1|Wh1]
      const int row = ch >> 8, k8 = (ch & 255) * 8;
      const int col = c0 + row;
      const float* s = (k8 < 1024) ? P.Wx + ((size_t)(3 * 1024 + col)) * 1024 + k8
                                   : P.Wh + ((size_t)(3 * 1024 + col)) * 1024 + (k8 - 1024);
      stage_row8(lds, row, 4096, k8, s);
    }
    for (int ch = tid; ch < 16 * 256; ch += 256) {  // g
      const int row = ch >> 8, k8 = (ch & 255) * 8;
      const int col = c0 + row;
      const float* s = (k8 < 1024) ? P.Wx + ((size_t)(5 * 1024 + col)) * 1024 + k8
                                   : P.Wh + ((size_t)(5 * 1024 + col)) * 1024 + (k8 - 1024);
      stage_row8(lds + 65536, row, 4096, k8, s);
    }
  } else {
    for (int ch = tid; ch < 16 * 256; ch += 256) {  // r, K=2048
      const int row = ch >> 8, k8 = (ch & 255) * 8;
      const int col = c0 + row;
      const float* s = (k8 < 1024) ? P.Wx + ((size_t)(4 * 1024 + col)) * 1024 + k8
                                   : P.Wh + ((size_t)(4 * 1024 + col)) * 1024 + (k8 - 1024);
      stage_row8(lds, row, 4096, k8, s);
    }
    for (int ch = tid; ch < 16 * 128; ch += 256) {  // Why
      const int row = ch >> 7, k8 = (ch & 127) * 8;
      stage_row8(lds + 65536, row, 2048, k8, P.Why + ((size_t)(c0 + row)) * 1024 + k8);
    }
  }
  __syncthreads();

  // per-role constants
  const int m0w = wv * 32;              // MT=2 roles (L0, L1r/OUT)
  const int m0z = mh * 64 + wv * 16;    // L1zg (MT=1)
  float bz = 0.f, bg = 0.f, br = 0.f, byv = 0.f;
  if (role == 1) {
    bz = P.bh[3 * 1024 + c0 + r];
    bg = P.bh[5 * 1024 + c0 + r];
  } else if (role == 2) {
    br = P.bh[4 * 1024 + c0 + r];
    byv = P.by[c0 + r];
  }

  float h0reg[8] = {}, z0reg[8] = {};  // L0
  float h1reg[4] = {}, z1reg[4] = {};  // L1zg

  // gx addend prefetch (L0 only)
  bf16x4 pz[2] = {}, pr[2] = {}, pg[2] = {};
  if (role == 0) {
    const bf16* gxz = P.gx0T + ((size_t)0 * 3072 + c0 + r) * 128;
#pragma unroll
    for (int f = 0; f < 2; ++f) {
      pz[f] = *reinterpret_cast<const bf16x4*>(gxz + m0w + f * 16 + kq * 4);
      pr[f] = *reinterpret_cast<const bf16x4*>(gxz + (size_t)1024 * 128 + m0w + f * 16 + kq * 4);
    }
  }

  int gen = 0;
  for (int i = 0; i < 514; ++i) {
    // parity buffers: read what was written last iteration, write the other
    const bf16* h0cur = ((i & 1) ? P.h0a : P.h0b);  // h0[i-1]
    bf16* h0nxt = ((i & 1) ? P.h0b : P.h0a);        // h0[i]
    const bf16* h1rd = ((i & 1) ? P.h1a : P.h1b);   // h1[i-2]
    bf16* h1wr = ((i & 1) ? P.h1b : P.h1a);         // h1[i-1]

    // ================= PHASE A =================
    gbar(P.bar, gen++);

    if (role == 0) {
      if (i < 512) {
        const bf16* gxg = P.gx0T + ((size_t)i * 3072 + 2048 + c0 + r) * 128;
#pragma unroll
        for (int f = 0; f < 2; ++f)
          pg[f] = *reinterpret_cast<const bf16x4*>(gxg + m0w + f * 16 + kq * 4);
        f32x4 acc[2][2] = {};
        mmA<2, 2, 2048>(h0cur, lds, 0, acc, m0w, r, kq);
#pragma unroll
        for (int f = 0; f < 2; ++f)
#pragma unroll
          for (int j = 0; j < 4; ++j) {
            const int ii = f * 4 + j;
            const int m = m0w + f * 16 + kq * 4 + j;
            z0reg[ii] = sigmf(acc[f][0][j] + (float)pz[f][j]);
            const float rv = sigmf(acc[f][1][j] + (float)pr[f][j]);
            st2_llc(P.rh0M + (size_t)m * 1024 + c0 + r, (bf16)(rv * h0reg[ii]));
          }
      }
    } else if (role == 1) {
      if (i >= 1 && i <= 512) {  // z1 for L1 step t=i-1
        f32x4 acc[1][1] = {};
        mmA<1, 1, 4096>(h0cur, lds, 0, acc, m0z, r, kq);
        mmA<1, 1, 4096>(h1rd, lds, 1024, acc, m0z, r, kq);
#pragma unroll
        for (int j = 0; j < 4; ++j) z1reg[j] = sigmf(acc[0][0][j] + bz);
      }
    } else {
      if (i >= 1 && i <= 512) {  // r1 for step t=i-1 -> rh1 = r * h1[t-1]
        float hp[2][4];
#pragma unroll
        for (int f = 0; f < 2; ++f)
#pragma unroll
          for (int j = 0; j < 4; ++j)
            hp[f][j] = ldh_sc(h1rd + (size_t)(m0w + f * 16 + kq * 4 + j) * 1024 + c0 + r);
        f32x4 acc[2][1] = {};
        mmA<2, 1, 4096>(h0cur, lds, 0, acc, m0w, r, kq);
        mmA<2, 1, 4096>(h1rd, lds, 1024, acc, m0w, r, kq);
#pragma unroll
        for (int f = 0; f < 2; ++f)
#pragma unroll
          for (int j = 0; j < 4; ++j) {
            const int m = m0w + f * 16 + kq * 4 + j;
            const float rv = sigmf(acc[f][0][j] + br);
            st2_llc(P.rh1M + (size_t)m * 1024 + c0 + r, (bf16)(rv * hp[f][j]));
          }
      }
    }

    // ================= PHASE B =================
    gbar(P.bar, gen++);

    if (role == 0) {
      if (i < 512) {
        if (i + 1 < 512) {  // prefetch z/r addends for step i+1
          const bf16* gxz = P.gx0T + ((size_t)(i + 1) * 3072 + c0 + r) * 128;
#pragma unroll
          for (int f = 0; f < 2; ++f) {
            pz[f] = *reinterpret_cast<const bf16x4*>(gxz + m0w + f * 16 + kq * 4);
            pr[f] =
                *reinterpret_cast<const bf16x4*>(gxz + (size_t)1024 * 128 + m0w + f * 16 + kq * 4);
          }
        }
        f32x4 acc[2][1] = {};
        mmA<2, 1, 2048>(P.rh0M, lds + 65536, 0, acc, m0w, r, kq);
#pragma unroll
        for (int f = 0; f < 2; ++f)
#pragma unroll
          for (int j = 0; j < 4; ++j) {
            const int ii = f * 4 + j;
            const int m = m0w + f * 16 + kq * 4 + j;
            const float gv = tanhf(acc[f][0][j] + (float)pg[f][j]);
            const float hn = z0reg[ii] * h0reg[ii] + (1.f - z0reg[ii]) * gv;
            h0reg[ii] = hn;
            st2_llc(h0nxt + (size_t)m * 1024 + c0 + r, (bf16)hn);
          }
      }
    } else if (role == 1) {
      if (i >= 1 && i <= 512) {  // g1 for step t=i-1, update h1
        f32x4 acc[1][1] = {};
        mmA<1, 1, 4096>(h0cur, lds + 65536, 0, acc, m0z, r, kq);
        mmA<1, 1, 4096>(P.rh1M, lds + 65536, 1024, acc, m0z, r, kq);
#pragma unroll
        for (int j = 0; j < 4; ++j) {
          const int m = m0z + kq * 4 + j;
          const float gv = tanhf(acc[0][0][j] + bg);
          const float hn = z1reg[j] * h1reg[j] + (1.f - z1reg[j]) * gv;
          h1reg[j] = hn;
          st2_llc(h1wr + (size_t)m * 1024 + c0 + r, (bf16)hn);
        }
      }
    } else {
      if (i >= 2) {  // y for step t2=i-2 from h1rd (=h1[i-2])
        f32x4 acc[2][1] = {};
        mmA<2, 1, 2048>(h1rd, lds + 65536, 0, acc, m0w, r, kq);
        const int t2 = i - 2;
#pragma unroll
        for (int f = 0; f < 2; ++f)
#pragma unroll
          for (int j = 0; j < 4; ++j) {
            const int m = m0w + f * 16 + kq * 4 + j;
            P.out[((size_t)m * 512 + t2) * 1024 + c0 + r] = acc[f][0][j] + byv;
          }
      }
    }
  }

  // ---- final hidden state from registers: out_hidden[b][layer][1024] ----
  float* hid = P.out + (size_t)128 * 512 * 1024;
  if (role == 0) {
#pragma unroll
    for (int f = 0; f < 2; ++f)
#pragma unroll
      for (int j = 0; j < 4; ++j) {
        const int m = m0w + f * 16 + kq * 4 + j;
        hid[(size_t)m * 2048 + c0 + r] = h0reg[f * 4 + j];
      }
  } else if (role == 1) {
#pragma unroll
    for (int j = 0; j < 4; ++j) {
      const int m = m0z + kq * 4 + j;
      hid[(size_t)m * 2048 + 1024 + c0 + r] = h1reg[j];
    }
  }
}

extern "C" void kernel_launch(void* const* d_in, const int* in_sizes, int n_in,
                              void* d_out, int out_size, void* d_ws, size_t ws_size,
                              hipStream_t stream) {
  const float* x = (const float*)d_in[0];
  const float* Wx = (const float*)d_in[1];
  const float* Wh = (const float*)d_in[2];
  const float* bh = (const float*)d_in[3];
  const float* Why = (const float*)d_in[4];
  const float* by = (const float*)d_in[5];
  float* out = (float*)d_out;

  char* ws = (char*)d_ws;
  size_t off = 0;
  auto alloc = [&](size_t bytes) -> void* {
    void* p = ws + off;
    off += (bytes + 255) & ~(size_t)255;
    return p;
  };
  bf16* Wxb = (bf16*)alloc((size_t)3 * 1024 * 1024 * 2);    // layer-0 Wx bf16
  bf16* gx0T = (bf16*)alloc((size_t)512 * 3072 * 128 * 2);  // 384 MB
  bf16* h0a = (bf16*)alloc(262144);
  bf16* h0b = (bf16*)alloc(262144);
  bf16* h1a = (bf16*)alloc(262144);
  bf16* h1b = (bf16*)alloc(262144);
  bf16* rh0M = (bf16*)alloc(262144);
  bf16* rh1M = (bf16*)alloc(262144);
  int* bar = (int*)alloc(4096);
  (void)ws_size;

  hipFuncSetAttribute((const void*)k_gru, hipFuncAttributeMaxDynamicSharedMemorySize, 131072);

  k_cast4<<<512, 256, 0, stream>>>(Wx, Wxb, (3 * 1024 * 1024) / 4);
  hipMemsetAsync(h0a, 0, 262144, stream);
  hipMemsetAsync(h0b, 0, 262144, stream);
  hipMemsetAsync(h1a, 0, 262144, stream);
  hipMemsetAsync(h1b, 0, 262144, stream);
  hipMemsetAsync(bar, 0, 4096, stream);

  k_gx0T<<<12288, 256, 0, stream>>>(x, Wxb, bh, gx0T);

  GP gp{Wx, Wh, bh, by, Why, gx0T, h0a, h0b, h1a, h1b, rh0M, rh1M, out, bar};
  void* kargs[] = {&gp};
  hipLaunchCooperativeKernel((void*)k_gru, dim3(256), dim3(256), kargs, 131072, stream);
}

// Round 7
// 21038.457 us; speedup vs baseline: 1.3018x; 1.3018x over previous
//
#include <hip/hip_runtime.h>
#include <hip/hip_bf16.h>

// MultilayerGRU: B=128, S=512, H=1024, L=2, O=1024
// Round 7: per-XCD relay with runtime XCD census (deadlock-proof).
//  - masters LLC-only (sc0sc1 writes; only ever read via agent-scope atomics)
//  - per phase: grid barrier -> XCD-cooperative relay of the 2 needed panels
//    into an XCD-private L2 buffer -> per-XCD barrier (dynamic count) +
//    L1-only buffer_inv -> compute with normal cached loads (L2-served)
//  - fabric broadcast traffic per phase: ~80 MB -> 4 MB

typedef __bf16 bf16;
typedef __attribute__((ext_vector_type(8))) __bf16 bf16x8;
typedef __attribute__((ext_vector_type(4))) __bf16 bf16x4;
typedef __attribute__((ext_vector_type(4))) float f32x4;

#define MFMA16(a, b, c) __builtin_amdgcn_mfma_f32_16x16x32_bf16(a, b, c, 0, 0, 0)

static __device__ __forceinline__ bf16x8 ldfrag(const bf16* p) {
  return *reinterpret_cast<const bf16x8*>(p);
}
static __device__ __forceinline__ float sigmf(float x) { return 1.f / (1.f + __expf(-x)); }

// write-through store: lands at the device coherence point, no dirty L2 lines
static __device__ __forceinline__ void st2_llc(bf16* p, bf16 v) {
  unsigned u = (unsigned)__builtin_bit_cast(unsigned short, v);
  asm volatile("global_store_short %0, %1, off sc0 sc1" :: "v"(p), "v"(u) : "memory");
}
static __device__ __forceinline__ int get_xcd() {
  unsigned x;
  asm volatile("s_getreg_b32 %0, hwreg(HW_REG_XCC_ID)" : "=s"(x));
  return (int)(x & 7);
}

// ---------------- weight cast (layer-0 Wx only, for gx0 GEMM) ----------------
__global__ void k_cast4(const float* __restrict__ s, bf16* __restrict__ d, int n4) {
  int i = blockIdx.x * blockDim.x + threadIdx.x;
  int st = gridDim.x * blockDim.x;
  for (; i < n4; i += st) {
    float4 v = reinterpret_cast<const float4*>(s)[i];
    bf16x4 o = {(bf16)v.x, (bf16)v.y, (bf16)v.z, (bf16)v.w};
    *reinterpret_cast<bf16x4*>(d + (size_t)i * 4) = o;
  }
}

// ---------------- gx0T[s][col][b] = (x @ Wx0^T + bh0) transposed ----------------
__global__ __launch_bounds__(256) void k_gx0T(const float* __restrict__ x,
                                              const bf16* __restrict__ wx0,
                                              const float* __restrict__ bh,
                                              bf16* __restrict__ gx0T) {
  const int lane = threadIdx.x & 63;
  const int gw = blockIdx.x * 4 + (threadIdx.x >> 6);
  const int NT = 3072 / 64;  // 48
  const int tm = gw / NT, tn = gw % NT;
  const int m0 = tm * 64, n0 = tn * 64;
  const int r = lane & 15, kq = lane >> 4;
  f32x4 acc[4][4] = {};
  for (int k0 = 0; k0 < 1024; k0 += 32) {
    const int k = k0 + kq * 8;
    bf16x8 a[4], b[4];
#pragma unroll
    for (int mi = 0; mi < 4; ++mi) {
      const int m = m0 + mi * 16 + r;
      const int bb = m & 127, s = m >> 7;
      const float* xp = x + ((size_t)(bb * 512 + s)) * 1024 + k;
      float4 lo = *reinterpret_cast<const float4*>(xp);
      float4 hi = *reinterpret_cast<const float4*>(xp + 4);
      bf16x8 av;
      av[0] = (bf16)lo.x; av[1] = (bf16)lo.y; av[2] = (bf16)lo.z; av[3] = (bf16)lo.w;
      av[4] = (bf16)hi.x; av[5] = (bf16)hi.y; av[6] = (bf16)hi.z; av[7] = (bf16)hi.w;
      a[mi] = av;
    }
#pragma unroll
    for (int ni = 0; ni < 4; ++ni)
      b[ni] = ldfrag(wx0 + (size_t)(n0 + ni * 16 + r) * 1024 + k);
#pragma unroll
    for (int mi = 0; mi < 4; ++mi)
#pragma unroll
      for (int ni = 0; ni < 4; ++ni) acc[mi][ni] = MFMA16(a[mi], b[ni], acc[mi][ni]);
  }
#pragma unroll
  for (int mi = 0; mi < 4; ++mi) {
#pragma unroll
    for (int ni = 0; ni < 4; ++ni) {
      const int col = n0 + ni * 16 + r;
      const float bias = bh[col];
      bf16x4 v;
#pragma unroll
      for (int j = 0; j < 4; ++j) v[j] = (bf16)(acc[mi][ni][j] + bias);
      const int m = m0 + mi * 16 + kq * 4;  // 4 consecutive b's (same s)
      const int s = m >> 7, bb = m & 127;
      *reinterpret_cast<bf16x4*>(gx0T + ((size_t)s * 3072 + col) * 128 + bb) = v;
    }
  }
}

// ---------------- persistent GRU scan ----------------
struct GP {
  const float* Wx;
  const float* Wh;
  const float* bh;
  const float* by;
  const float* Why;
  const bf16* gx0T;
  bf16* h0M;    // masters (LLC-only)
  bf16* h1Ma;   // h1 parity masters
  bf16* h1Mb;
  bf16* rh0M;
  bf16* rh1M;
  char* xcop;   // per-XCD private copies: 8 x 4 panels x 256KB
  float* out;
  int* bar;
};

// flattened grid barrier: 8 arrival lines, poller sums all 8
__device__ __forceinline__ void gbar(int* bar, int gen) {
  asm volatile("s_waitcnt vmcnt(0)" ::: "memory");
  __syncthreads();
  if (threadIdx.x == 0) {
    atomicAdd(bar + (blockIdx.x & 7) * 32, 1);
    const int want = (gen + 1) * 256;
    for (;;) {
      int sum = 0;
#pragma unroll
      for (int g = 0; g < 8; ++g)
        sum += __hip_atomic_load(bar + g * 32, __ATOMIC_RELAXED, __HIP_MEMORY_SCOPE_AGENT);
      if (sum >= want) break;
      __builtin_amdgcn_s_sleep(2);
    }
  }
  __syncthreads();
}

// per-XCD barrier with runtime count, then L1-only invalidate
__device__ __forceinline__ void xbar(int* xf, int xgen, int xcnt) {
  asm volatile("s_waitcnt vmcnt(0)" ::: "memory");
  __syncthreads();
  if (threadIdx.x == 0) {
    atomicAdd(xf, 1);
    while (__hip_atomic_load(xf, __ATOMIC_RELAXED, __HIP_MEMORY_SCOPE_AGENT) <
           (xgen + 1) * xcnt)
      __builtin_amdgcn_s_sleep(1);
  }
  __syncthreads();
  asm volatile("buffer_inv\ns_waitcnt vmcnt(0)" ::: "memory");  // L1 invalidate
}

// XCD-cooperative copy of two 256KB masters into the XCD-private L2 buffer
__device__ __forceinline__ void relay(const bf16* __restrict__ s0, bf16* __restrict__ d0,
                                      const bf16* __restrict__ s1, bf16* __restrict__ d1,
                                      int lid, int xcnt, int tid) {
  const int step = xcnt * 256;
  for (int g = lid * 256 + tid; g < 32768; g += step) {
    const unsigned long long* src;
    unsigned long long* dst;
    int gg = g;
    if (g < 16384) {
      src = (const unsigned long long*)s0;
      dst = (unsigned long long*)d0;
    } else {
      gg = g - 16384;
      src = (const unsigned long long*)s1;
      dst = (unsigned long long*)d1;
    }
    unsigned long long a =
        __hip_atomic_load(src + (size_t)gg * 2, __ATOMIC_RELAXED, __HIP_MEMORY_SCOPE_AGENT);
    unsigned long long b =
        __hip_atomic_load(src + (size_t)gg * 2 + 1, __ATOMIC_RELAXED, __HIP_MEMORY_SCOPE_AGENT);
    dst[(size_t)gg * 2] = a;
    dst[(size_t)gg * 2 + 1] = b;
  }
}

__device__ __forceinline__ void stage_row8(char* dst, int row, int rb, int k8,
                                           const float* __restrict__ src) {
  const float4 f0 = *reinterpret_cast<const float4*>(src);
  const float4 f1 = *reinterpret_cast<const float4*>(src + 4);
  bf16x8 v;
  v[0] = (bf16)f0.x; v[1] = (bf16)f0.y; v[2] = (bf16)f0.z; v[3] = (bf16)f0.w;
  v[4] = (bf16)f1.x; v[5] = (bf16)f1.y; v[6] = (bf16)f1.z; v[7] = (bf16)f1.w;
  *reinterpret_cast<bf16x8*>(dst + (size_t)row * rb + ((k8 * 2) ^ ((row & 7) << 4))) = v;
}

// A from XCD-private L2 copy (normal cached loads), B from LDS
template <int MT, int NT, int RB>
__device__ __forceinline__ void mmA(const bf16* __restrict__ A, const char* __restrict__ ldsb,
                                    const int kloff, f32x4 (&acc)[MT][NT], const int m0,
                                    const int r, const int kq) {
#pragma unroll 8
  for (int k0 = 0; k0 < 1024; k0 += 32) {
    const int k = k0 + kq * 8;
    bf16x8 a[MT];
#pragma unroll
    for (int mi = 0; mi < MT; ++mi)
      a[mi] = ldfrag(A + (size_t)(m0 + mi * 16 + r) * 1024 + k);
#pragma unroll
    for (int nt = 0; nt < NT; ++nt) {
      const bf16x8 b = *reinterpret_cast<const bf16x8*>(
          ldsb + (size_t)(nt * 16 + r) * RB + (((kloff + k) * 2) ^ ((r & 7) << 4)));
#pragma unroll
      for (int mi = 0; mi < MT; ++mi) acc[mi][nt] = MFMA16(a[mi], b, acc[mi][nt]);
    }
  }
}

__global__ void __launch_bounds__(256, 1) k_gru(GP P) {
  extern __shared__ char lds[];
  __shared__ int s_lid, s_cnt, s_xcd;
  const int w = blockIdx.x;
  const int tid = threadIdx.x;
  const int r = tid & 15, kq = (tid >> 4) & 3, wv = tid >> 6;

  // ---- role geometry ----
  int c0, mh = 0, role;
  if (w < 64) { role = 0; c0 = w * 16; }
  else if (w < 192) { role = 1; c0 = ((w - 64) >> 1) * 16; mh = (w - 64) & 1; }
  else { role = 2; c0 = (w - 192) * 16; }

  // ---- XCD census (physical placement discovered at runtime) ----
  if (tid == 0) {
    const int xcd = get_xcd();
    s_xcd = xcd;
    s_lid = atomicAdd(P.bar + 512 + xcd, 1);
  }

  // ---- stage weights into LDS (once, f32 -> bf16, XOR-swizzled) ----
  if (role == 0) {
    for (int ch = tid; ch < 32 * 128; ch += 256) {  // rows 0-15 z, 16-31 r, K=1024
      const int row = ch >> 7, k8 = (ch & 127) * 8;
      const int gate = row >> 4, col = c0 + (row & 15);
      stage_row8(lds, row, 2048, k8, P.Wh + ((size_t)(gate * 1024 + col)) * 1024 + k8);
    }
    for (int ch = tid; ch < 16 * 128; ch += 256) {  // g
      const int row = ch >> 7, k8 = (ch & 127) * 8;
      stage_row8(lds + 65536, row, 2048, k8,
                 P.Wh + ((size_t)(2 * 1024 + c0 + row)) * 1024 + k8);
    }
  } else if (role == 1) {
    for (int ch = tid; ch < 16 * 256; ch += 256) {  // z, K=2048 concat [Wx1|Wh1]
      const int row = ch >> 8, k8 = (ch & 255) * 8;
      const int col = c0 + row;
      const float* s = (k8 < 1024) ? P.Wx + ((size_t)(3 * 1024 + col)) * 1024 + k8
                                   : P.Wh + ((size_t)(3 * 1024 + col)) * 1024 + (k8 - 1024);
      stage_row8(lds, row, 4096, k8, s);
    }
    for (int ch = tid; ch < 16 * 256; ch += 256) {  // g
      const int row = ch >> 8, k8 = (ch & 255) * 8;
      const int col = c0 + row;
      const float* s = (k8 < 1024) ? P.Wx + ((size_t)(5 * 1024 + col)) * 1024 + k8
                                   : P.Wh + ((size_t)(5 * 1024 + col)) * 1024 + (k8 - 1024);
      stage_row8(lds + 65536, row, 4096, k8, s);
    }
  } else {
    for (int ch = tid; ch < 16 * 256; ch += 256) {  // r, K=2048
      const int row = ch >> 8, k8 = (ch & 255) * 8;
      const int col = c0 + row;
      const float* s = (k8 < 1024) ? P.Wx + ((size_t)(4 * 1024 + col)) * 1024 + k8
                                   : P.Wh + ((size_t)(4 * 1024 + col)) * 1024 + (k8 - 1024);
      stage_row8(lds, row, 4096, k8, s);
    }
    for (int ch = tid; ch < 16 * 128; ch += 256) {  // Why
      const int row = ch >> 7, k8 = (ch & 127) * 8;
      stage_row8(lds + 65536, row, 2048, k8, P.Why + ((size_t)(c0 + row)) * 1024 + k8);
    }
  }
  __syncthreads();

  int gen = 0;
  gbar(P.bar, gen++);  // census complete everywhere
  if (tid == 0)
    s_cnt = __hip_atomic_load(P.bar + 512 + s_xcd, __ATOMIC_RELAXED, __HIP_MEMORY_SCOPE_AGENT);
  __syncthreads();
  const int xcd = s_xcd, lid = s_lid, xcnt = s_cnt;

  char* xb = P.xcop + (size_t)xcd * (4 * 262144);
  bf16* xh0 = (bf16*)xb;
  bf16* xh1 = (bf16*)(xb + 262144);
  bf16* xrh0 = (bf16*)(xb + 2 * 262144);
  bf16* xrh1 = (bf16*)(xb + 3 * 262144);
  int* xf = P.bar + 576 + xcd * 16;
  int xgen = 0;

  // per-role constants
  const int m0w = wv * 32;              // MT=2 roles (L0, L1r/OUT)
  const int m0z = mh * 64 + wv * 16;    // L1zg (MT=1)
  float bz = 0.f, bg = 0.f, br = 0.f, byv = 0.f;
  if (role == 1) {
    bz = P.bh[3 * 1024 + c0 + r];
    bg = P.bh[5 * 1024 + c0 + r];
  } else if (role == 2) {
    br = P.bh[4 * 1024 + c0 + r];
    byv = P.by[c0 + r];
  }

  float h0reg[8] = {}, z0reg[8] = {};  // L0
  float h1reg[4] = {}, z1reg[4] = {};  // L1zg

  // gx addend prefetch (L0 only)
  bf16x4 pz[2] = {}, pr[2] = {}, pg[2] = {};
  if (role == 0) {
    const bf16* gxz = P.gx0T + ((size_t)0 * 3072 + c0 + r) * 128;
#pragma unroll
    for (int f = 0; f < 2; ++f) {
      pz[f] = *reinterpret_cast<const bf16x4*>(gxz + m0w + f * 16 + kq * 4);
      pr[f] = *reinterpret_cast<const bf16x4*>(gxz + (size_t)1024 * 128 + m0w + f * 16 + kq * 4);
    }
  }

  for (int i = 0; i < 514; ++i) {
    // h1 parity masters: W(i) = (i&1)?h1Ma:h1Mb holds h1[i-1] after phase B
    bf16* h1dst = (i & 1) ? P.h1Ma : P.h1Mb;
    const bf16* h1src = (i & 1) ? P.h1Mb : P.h1Ma;  // holds h1[i-2]

    // ================= PHASE A =================
    gbar(P.bar, gen++);
    relay(P.h0M, xh0, h1src, xh1, lid, xcnt, tid);  // h0[i-1], h1[i-2] -> XCD L2
    xbar(xf, xgen++, xcnt);

    if (role == 0) {
      if (i < 512) {
        const bf16* gxg = P.gx0T + ((size_t)i * 3072 + 2048 + c0 + r) * 128;
#pragma unroll
        for (int f = 0; f < 2; ++f)
          pg[f] = *reinterpret_cast<const bf16x4*>(gxg + m0w + f * 16 + kq * 4);
        f32x4 acc[2][2] = {};
        mmA<2, 2, 2048>(xh0, lds, 0, acc, m0w, r, kq);
#pragma unroll
        for (int f = 0; f < 2; ++f)
#pragma unroll
          for (int j = 0; j < 4; ++j) {
            const int ii = f * 4 + j;
            const int m = m0w + f * 16 + kq * 4 + j;
            z0reg[ii] = sigmf(acc[f][0][j] + (float)pz[f][j]);
            const float rv = sigmf(acc[f][1][j] + (float)pr[f][j]);
            st2_llc(P.rh0M + (size_t)m * 1024 + c0 + r, (bf16)(rv * h0reg[ii]));
          }
      }
    } else if (role == 1) {
      if (i >= 1 && i <= 512) {  // z1 for L1 step t=i-1
        f32x4 acc[1][1] = {};
        mmA<1, 1, 4096>(xh0, lds, 0, acc, m0z, r, kq);
        mmA<1, 1, 4096>(xh1, lds, 1024, acc, m0z, r, kq);
#pragma unroll
        for (int j = 0; j < 4; ++j) z1reg[j] = sigmf(acc[0][0][j] + bz);
      }
    } else {
      if (i >= 1 && i <= 512) {  // r1 for step t=i-1 -> rh1 = r * h1[t-1]
        float hp[2][4];
#pragma unroll
        for (int f = 0; f < 2; ++f)
#pragma unroll
          for (int j = 0; j < 4; ++j)
            hp[f][j] = (float)xh1[(size_t)(m0w + f * 16 + kq * 4 + j) * 1024 + c0 + r];
        f32x4 acc[2][1] = {};
        mmA<2, 1, 4096>(xh0, lds, 0, acc, m0w, r, kq);
        mmA<2, 1, 4096>(xh1, lds, 1024, acc, m0w, r, kq);
#pragma unroll
        for (int f = 0; f < 2; ++f)
#pragma unroll
          for (int j = 0; j < 4; ++j) {
            const int m = m0w + f * 16 + kq * 4 + j;
            const float rv = sigmf(acc[f][0][j] + br);
            st2_llc(P.rh1M + (size_t)m * 1024 + c0 + r, (bf16)(rv * hp[f][j]));
          }
      }
    }

    // ================= PHASE B =================
    gbar(P.bar, gen++);
    relay(P.rh0M, xrh0, P.rh1M, xrh1, lid, xcnt, tid);
    xbar(xf, xgen++, xcnt);

    if (role == 0) {
      if (i < 512) {
        if (i + 1 < 512) {  // prefetch z/r addends for step i+1
          const bf16* gxz = P.gx0T + ((size_t)(i + 1) * 3072 + c0 + r) * 128;
#pragma unroll
          for (int f = 0; f < 2; ++f) {
            pz[f] = *reinterpret_cast<const bf16x4*>(gxz + m0w + f * 16 + kq * 4);
            pr[f] =
                *reinterpret_cast<const bf16x4*>(gxz + (size_t)1024 * 128 + m0w + f * 16 + kq * 4);
          }
        }
        f32x4 acc[2][1] = {};
        mmA<2, 1, 2048>(xrh0, lds + 65536, 0, acc, m0w, r, kq);
#pragma unroll
        for (int f = 0; f < 2; ++f)
#pragma unroll
          for (int j = 0; j < 4; ++j) {
            const int ii = f * 4 + j;
            const int m = m0w + f * 16 + kq * 4 + j;
            const float gv = tanhf(acc[f][0][j] + (float)pg[f][j]);
            const float hn = z0reg[ii] * h0reg[ii] + (1.f - z0reg[ii]) * gv;
            h0reg[ii] = hn;
            st2_llc(P.h0M + (size_t)m * 1024 + c0 + r, (bf16)hn);
          }
      }
    } else if (role == 1) {
      if (i >= 1 && i <= 512) {  // g1 for step t=i-1, update h1
        f32x4 acc[1][1] = {};
        mmA<1, 1, 4096>(xh0, lds + 65536, 0, acc, m0z, r, kq);
        mmA<1, 1, 4096>(xrh1, lds + 65536, 1024, acc, m0z, r, kq);
#pragma unroll
        for (int j = 0; j < 4; ++j) {
          const int m = m0z + kq * 4 + j;
          const float gv = tanhf(acc[0][0][j] + bg);
          const float hn = z1reg[j] * h1reg[j] + (1.f - z1reg[j]) * gv;
          h1reg[j] = hn;
          st2_llc(h1dst + (size_t)m * 1024 + c0 + r, (bf16)hn);
        }
      }
    } else {
      if (i >= 2) {  // y for step t2=i-2 from xh1 (=h1[i-2])
        f32x4 acc[2][1] = {};
        mmA<2, 1, 2048>(xh1, lds + 65536, 0, acc, m0w, r, kq);
        const int t2 = i - 2;
#pragma unroll
        for (int f = 0; f < 2; ++f)
#pragma unroll
          for (int j = 0; j < 4; ++j) {
            const int m = m0w + f * 16 + kq * 4 + j;
            P.out[((size_t)m * 512 + t2) * 1024 + c0 + r] = acc[f][0][j] + byv;
          }
      }
    }
  }

  // ---- final hidden state from registers: out_hidden[b][layer][1024] ----
  float* hid = P.out + (size_t)128 * 512 * 1024;
  if (role == 0) {
#pragma unroll
    for (int f = 0; f < 2; ++f)
#pragma unroll
      for (int j = 0; j < 4; ++j) {
        const int m = m0w + f * 16 + kq * 4 + j;
        hid[(size_t)m * 2048 + c0 + r] = h0reg[f * 4 + j];
      }
  } else if (role == 1) {
#pragma unroll
    for (int j = 0; j < 4; ++j) {
      const int m = m0z + kq * 4 + j;
      hid[(size_t)m * 2048 + 1024 + c0 + r] = h1reg[j];
    }
  }
}

extern "C" void kernel_launch(void* const* d_in, const int* in_sizes, int n_in,
                              void* d_out, int out_size, void* d_ws, size_t ws_size,
                              hipStream_t stream) {
  const float* x = (const float*)d_in[0];
  const float* Wx = (const float*)d_in[1];
  const float* Wh = (const float*)d_in[2];
  const float* bh = (const float*)d_in[3];
  const float* Why = (const float*)d_in[4];
  const float* by = (const float*)d_in[5];
  float* out = (float*)d_out;

  char* ws = (char*)d_ws;
  size_t off = 0;
  auto alloc = [&](size_t bytes) -> void* {
    void* p = ws + off;
    off += (bytes + 255) & ~(size_t)255;
    return p;
  };
  bf16* Wxb = (bf16*)alloc((size_t)3 * 1024 * 1024 * 2);    // layer-0 Wx bf16
  bf16* gx0T = (bf16*)alloc((size_t)512 * 3072 * 128 * 2);  // 384 MB
  bf16* h0M = (bf16*)alloc(262144);
  bf16* h1Ma = (bf16*)alloc(262144);
  bf16* h1Mb = (bf16*)alloc(262144);
  bf16* rh0M = (bf16*)alloc(262144);
  bf16* rh1M = (bf16*)alloc(262144);
  char* xcop = (char*)alloc((size_t)8 * 4 * 262144);        // 8 MB
  int* bar = (int*)alloc(4096);
  (void)ws_size;

  hipFuncSetAttribute((const void*)k_gru, hipFuncAttributeMaxDynamicSharedMemorySize, 131072);

  k_cast4<<<512, 256, 0, stream>>>(Wx, Wxb, (3 * 1024 * 1024) / 4);
  hipMemsetAsync(h0M, 0, 262144, stream);
  hipMemsetAsync(h1Ma, 0, 262144, stream);
  hipMemsetAsync(h1Mb, 0, 262144, stream);
  hipMemsetAsync(bar, 0, 4096, stream);

  k_gx0T<<<12288, 256, 0, stream>>>(x, Wxb, bh, gx0T);

  GP gp{Wx, Wh, bh, by, Why, gx0T, h0M, h1Ma, h1Mb, rh0M, rh1M, xcop, out, bar};
  void* kargs[] = {&gp};
  hipLaunchCooperativeKernel((void*)k_gru, dim3(256), dim3(256), kargs, 131072, stream);
}

// Round 8
// 15671.837 us; speedup vs baseline: 1.7476x; 1.3424x over previous
//
#include <hip/hip_runtime.h>
#include <hip/hip_bf16.h>

// MultilayerGRU: B=128, S=512, H=1024, L=2, O=1024
// Round 8: decoupled producer-consumer groups, flag barriers, write-once seqs.
//  - L0 group (64 WG): own 512-step chain, 64-WG flag barrier
//  - L1 group (192 WG): z1/g1 (128) + r1/OUT (64), 192-WG flag barrier,
//    gated on L0 progress (release0) - always satisfied after startup
//  - h0seq/h1seq/rh0seq/rh1seq: write-once per step (sc0sc1 -> LLC);
//    readers use normal cached loads (first touch -> LLC; XCD L2 auto-relays)
//  - fallback (small ws): rh seqs -> parity-2 buffers + coherent sc reads

typedef __bf16 bf16;
typedef __attribute__((ext_vector_type(8))) __bf16 bf16x8;
typedef __attribute__((ext_vector_type(4))) __bf16 bf16x4;
typedef __attribute__((ext_vector_type(4))) float f32x4;

#define MFMA16(a, b, c) __builtin_amdgcn_mfma_f32_16x16x32_bf16(a, b, c, 0, 0, 0)

static __device__ __forceinline__ bf16x8 ldfrag(const bf16* p) {
  return *reinterpret_cast<const bf16x8*>(p);
}
static __device__ __forceinline__ float sigmf(float x) { return 1.f / (1.f + __expf(-x)); }

// write-through store: lands at the device coherence point (LLC)
static __device__ __forceinline__ void st2_llc(bf16* p, bf16 v) {
  unsigned u = (unsigned)__builtin_bit_cast(unsigned short, v);
  asm volatile("global_store_short %0, %1, off sc0 sc1" :: "v"(p), "v"(u) : "memory");
}
// coherent 16B fragment load from LLC (for fallback mode only)
static __device__ __forceinline__ bf16x8 ldA_sc(const bf16* p) {
  union { unsigned long long q[2]; bf16x8 v; } u;
  u.q[0] = __hip_atomic_load((const unsigned long long*)p, __ATOMIC_RELAXED,
                             __HIP_MEMORY_SCOPE_AGENT);
  u.q[1] = __hip_atomic_load(((const unsigned long long*)p) + 1, __ATOMIC_RELAXED,
                             __HIP_MEMORY_SCOPE_AGENT);
  return u.v;
}

// ---------------- weight cast (layer-0 Wx only, for gx0 GEMM) ----------------
__global__ void k_cast4(const float* __restrict__ s, bf16* __restrict__ d, int n4) {
  int i = blockIdx.x * blockDim.x + threadIdx.x;
  int st = gridDim.x * blockDim.x;
  for (; i < n4; i += st) {
    float4 v = reinterpret_cast<const float4*>(s)[i];
    bf16x4 o = {(bf16)v.x, (bf16)v.y, (bf16)v.z, (bf16)v.w};
    *reinterpret_cast<bf16x4*>(d + (size_t)i * 4) = o;
  }
}

// ---------------- gx0T[s][col][b] = (x @ Wx0^T + bh0) transposed ----------------
__global__ __launch_bounds__(256) void k_gx0T(const float* __restrict__ x,
                                              const bf16* __restrict__ wx0,
                                              const float* __restrict__ bh,
                                              bf16* __restrict__ gx0T) {
  const int lane = threadIdx.x & 63;
  const int gw = blockIdx.x * 4 + (threadIdx.x >> 6);
  const int NT = 3072 / 64;  // 48
  const int tm = gw / NT, tn = gw % NT;
  const int m0 = tm * 64, n0 = tn * 64;
  const int r = lane & 15, kq = lane >> 4;
  f32x4 acc[4][4] = {};
  for (int k0 = 0; k0 < 1024; k0 += 32) {
    const int k = k0 + kq * 8;
    bf16x8 a[4], b[4];
#pragma unroll
    for (int mi = 0; mi < 4; ++mi) {
      const int m = m0 + mi * 16 + r;
      const int bb = m & 127, s = m >> 7;
      const float* xp = x + ((size_t)(bb * 512 + s)) * 1024 + k;
      float4 lo = *reinterpret_cast<const float4*>(xp);
      float4 hi = *reinterpret_cast<const float4*>(xp + 4);
      bf16x8 av;
      av[0] = (bf16)lo.x; av[1] = (bf16)lo.y; av[2] = (bf16)lo.z; av[3] = (bf16)lo.w;
      av[4] = (bf16)hi.x; av[5] = (bf16)hi.y; av[6] = (bf16)hi.z; av[7] = (bf16)hi.w;
      a[mi] = av;
    }
#pragma unroll
    for (int ni = 0; ni < 4; ++ni)
      b[ni] = ldfrag(wx0 + (size_t)(n0 + ni * 16 + r) * 1024 + k);
#pragma unroll
    for (int mi = 0; mi < 4; ++mi)
#pragma unroll
      for (int ni = 0; ni < 4; ++ni) acc[mi][ni] = MFMA16(a[mi], b[ni], acc[mi][ni]);
  }
#pragma unroll
  for (int mi = 0; mi < 4; ++mi) {
#pragma unroll
    for (int ni = 0; ni < 4; ++ni) {
      const int col = n0 + ni * 16 + r;
      const float bias = bh[col];
      bf16x4 v;
#pragma unroll
      for (int j = 0; j < 4; ++j) v[j] = (bf16)(acc[mi][ni][j] + bias);
      const int m = m0 + mi * 16 + kq * 4;  // 4 consecutive b's (same s)
      const int s = m >> 7, bb = m & 127;
      *reinterpret_cast<bf16x4*>(gx0T + ((size_t)s * 3072 + col) * 128 + bb) = v;
    }
  }
}

// ---------------- persistent GRU scan ----------------
struct GP {
  const float* Wx;
  const float* Wh;
  const float* bh;
  const float* by;
  const float* Why;
  const bf16* gx0T;
  bf16* h0seq;   // 513 x [128][1024], write-once per slot
  bf16* h1seq;   // 513 x
  bf16* rh0seq;  // 512 x (or 2 x in fallback)
  bf16* rh1seq;
  float* out;
  int* bar;
  int sc_rh;     // 1 = fallback (parity + coherent reads)
};

// flag-array group barrier: arrive = own-slot store; master polls all, releases
__device__ __forceinline__ void group_bar(int* flags, int* release, int nw, int lw,
                                          bool master, int gen) {
  asm volatile("s_waitcnt vmcnt(0)" ::: "memory");
  __syncthreads();  // all waves' data stores drained
  if (threadIdx.x == 0)
    __hip_atomic_store(flags + lw * 16, gen, __ATOMIC_RELAXED, __HIP_MEMORY_SCOPE_AGENT);
  if (master) {
    if ((int)threadIdx.x < nw) {
      while (__hip_atomic_load(flags + threadIdx.x * 16, __ATOMIC_RELAXED,
                               __HIP_MEMORY_SCOPE_AGENT) < gen)
        __builtin_amdgcn_s_sleep(1);
    }
    __syncthreads();
    if (threadIdx.x == 0)
      __hip_atomic_store(release, gen, __ATOMIC_RELAXED, __HIP_MEMORY_SCOPE_AGENT);
  } else {
    if (threadIdx.x == 0) {
      while (__hip_atomic_load(release, __ATOMIC_RELAXED, __HIP_MEMORY_SCOPE_AGENT) < gen)
        __builtin_amdgcn_s_sleep(1);
    }
    __syncthreads();
  }
  asm volatile("" ::: "memory");
}

__device__ __forceinline__ void stage_row8(char* dst, int row, int rb, int k8,
                                           const float* __restrict__ src) {
  const float4 f0 = *reinterpret_cast<const float4*>(src);
  const float4 f1 = *reinterpret_cast<const float4*>(src + 4);
  bf16x8 v;
  v[0] = (bf16)f0.x; v[1] = (bf16)f0.y; v[2] = (bf16)f0.z; v[3] = (bf16)f0.w;
  v[4] = (bf16)f1.x; v[5] = (bf16)f1.y; v[6] = (bf16)f1.z; v[7] = (bf16)f1.w;
  *reinterpret_cast<bf16x8*>(dst + (size_t)row * rb + ((k8 * 2) ^ ((row & 7) << 4))) = v;
}

// A from global (cached or coherent per SC), B from LDS
template <int MT, int NT, int RB, bool SC = false>
__device__ __forceinline__ void mmA(const bf16* __restrict__ A, const char* __restrict__ ldsb,
                                    const int kloff, f32x4 (&acc)[MT][NT], const int m0,
                                    const int r, const int kq) {
#pragma unroll 8
  for (int k0 = 0; k0 < 1024; k0 += 32) {
    const int k = k0 + kq * 8;
    bf16x8 a[MT];
#pragma unroll
    for (int mi = 0; mi < MT; ++mi) {
      const bf16* p = A + (size_t)(m0 + mi * 16 + r) * 1024 + k;
      a[mi] = SC ? ldA_sc(p) : ldfrag(p);
    }
#pragma unroll
    for (int nt = 0; nt < NT; ++nt) {
      const bf16x8 b = *reinterpret_cast<const bf16x8*>(
          ldsb + (size_t)(nt * 16 + r) * RB + (((kloff + k) * 2) ^ ((r & 7) << 4)));
#pragma unroll
      for (int mi = 0; mi < MT; ++mi) acc[mi][nt] = MFMA16(a[mi], b, acc[mi][nt]);
    }
  }
}

__global__ void __launch_bounds__(256, 1) k_gru(GP P) {
  extern __shared__ char lds[];
  const int w = blockIdx.x;
  const int tid = threadIdx.x;
  const int r = tid & 15, kq = (tid >> 4) & 3, wv = tid >> 6;
  const size_t HB = 131072;  // elems per [128][1024] snapshot

  // ---- role geometry ----
  int c0, mh = 0, role;
  if (w < 64) { role = 0; c0 = w * 16; }
  else if (w < 192) { role = 1; c0 = ((w - 64) >> 1) * 16; mh = (w - 64) & 1; }
  else { role = 2; c0 = (w - 192) * 16; }

  // ---- stage weights into LDS (once, f32 -> bf16, XOR-swizzled) ----
  if (role == 0) {
    for (int ch = tid; ch < 32 * 128; ch += 256) {  // rows 0-15 z, 16-31 r, K=1024
      const int row = ch >> 7, k8 = (ch & 127) * 8;
      const int gate = row >> 4, col = c0 + (row & 15);
      stage_row8(lds, row, 2048, k8, P.Wh + ((size_t)(gate * 1024 + col)) * 1024 + k8);
    }
    for (int ch = tid; ch < 16 * 128; ch += 256) {  // g
      const int row = ch >> 7, k8 = (ch & 127) * 8;
      stage_row8(lds + 65536, row, 2048, k8,
                 P.Wh + ((size_t)(2 * 1024 + c0 + row)) * 1024 + k8);
    }
  } else if (role == 1) {
    for (int ch = tid; ch < 16 * 256; ch += 256) {  // z, K=2048 concat [Wx1|Wh1]
      const int row = ch >> 8, k8 = (ch & 255) * 8;
      const int col = c0 + row;
      const float* s = (k8 < 1024) ? P.Wx + ((size_t)(3 * 1024 + col)) * 1024 + k8
                                   : P.Wh + ((size_t)(3 * 1024 + col)) * 1024 + (k8 - 1024);
      stage_row8(lds, row, 4096, k8, s);
    }
    for (int ch = tid; ch < 16 * 256; ch += 256) {  // g
      const int row = ch >> 8, k8 = (ch & 255) * 8;
      const int col = c0 + row;
      const float* s = (k8 < 1024) ? P.Wx + ((size_t)(5 * 1024 + col)) * 1024 + k8
                                   : P.Wh + ((size_t)(5 * 1024 + col)) * 1024 + (k8 - 1024);
      stage_row8(lds + 65536, row, 4096, k8, s);
    }
  } else {
    for (int ch = tid; ch < 16 * 256; ch += 256) {  // r, K=2048
      const int row = ch >> 8, k8 = (ch & 255) * 8;
      const int col = c0 + row;
      const float* s = (k8 < 1024) ? P.Wx + ((size_t)(4 * 1024 + col)) * 1024 + k8
                                   : P.Wh + ((size_t)(4 * 1024 + col)) * 1024 + (k8 - 1024);
      stage_row8(lds, row, 4096, k8, s);
    }
    for (int ch = tid; ch < 16 * 128; ch += 256) {  // Why
      const int row = ch >> 7, k8 = (ch & 127) * 8;
      stage_row8(lds + 65536, row, 2048, k8, P.Why + ((size_t)(c0 + row)) * 1024 + k8);
    }
  }
  __syncthreads();

  const int m0w = wv * 32;            // MT=2 roles (L0, L1r/OUT)
  const int m0z = mh * 64 + wv * 16;  // L1zg (MT=1)
  float* hid = P.out + (size_t)128 * 512 * 1024;

  int* flags0 = P.bar;          // 64 slots, stride 16
  int* rel0 = P.bar + 1536;
  int* flags1 = P.bar + 2048;   // 192 slots, stride 16
  int* rel1 = P.bar + 5632;

  if (role == 0) {
    // =================== L0 chain (critical path) ===================
    const bool mast = (w == 0);
    float h0reg[8] = {}, z0reg[8] = {};
    bf16x4 pz[2], pr[2], pg[2];
    {
      const bf16* gxz = P.gx0T + (size_t)(c0 + r) * 128;
#pragma unroll
      for (int f = 0; f < 2; ++f) {
        pz[f] = *reinterpret_cast<const bf16x4*>(gxz + m0w + f * 16 + kq * 4);
        pr[f] = *reinterpret_cast<const bf16x4*>(gxz + (size_t)1024 * 128 + m0w + f * 16 + kq * 4);
      }
    }
    for (int t = 0; t < 512; ++t) {
      // ---- phase A: z, r ----
      const bf16* gxg = P.gx0T + ((size_t)t * 3072 + 2048 + c0 + r) * 128;
#pragma unroll
      for (int f = 0; f < 2; ++f)
        pg[f] = *reinterpret_cast<const bf16x4*>(gxg + m0w + f * 16 + kq * 4);
      bf16* rh0t = P.rh0seq + (P.sc_rh ? (size_t)(t & 1) : (size_t)t) * HB;
      f32x4 acc[2][2] = {};
      mmA<2, 2, 2048>(P.h0seq + (size_t)t * HB, lds, 0, acc, m0w, r, kq);
#pragma unroll
      for (int f = 0; f < 2; ++f)
#pragma unroll
        for (int j = 0; j < 4; ++j) {
          const int ii = f * 4 + j;
          const int m = m0w + f * 16 + kq * 4 + j;
          z0reg[ii] = sigmf(acc[f][0][j] + (float)pz[f][j]);
          const float rv = sigmf(acc[f][1][j] + (float)pr[f][j]);
          st2_llc(rh0t + (size_t)m * 1024 + c0 + r, (bf16)(rv * h0reg[ii]));
        }
      group_bar(flags0, rel0, 64, w, mast, 2 * t + 1);

      // ---- phase B: g + update ----
      if (t + 1 < 512) {
        const bf16* gxz = P.gx0T + ((size_t)(t + 1) * 3072 + c0 + r) * 128;
#pragma unroll
        for (int f = 0; f < 2; ++f) {
          pz[f] = *reinterpret_cast<const bf16x4*>(gxz + m0w + f * 16 + kq * 4);
          pr[f] =
              *reinterpret_cast<const bf16x4*>(gxz + (size_t)1024 * 128 + m0w + f * 16 + kq * 4);
        }
      }
      f32x4 acc2[2][1] = {};
      if (P.sc_rh) mmA<2, 1, 2048, true>(rh0t, lds + 65536, 0, acc2, m0w, r, kq);
      else mmA<2, 1, 2048, false>(rh0t, lds + 65536, 0, acc2, m0w, r, kq);
#pragma unroll
      for (int f = 0; f < 2; ++f)
#pragma unroll
        for (int j = 0; j < 4; ++j) {
          const int ii = f * 4 + j;
          const int m = m0w + f * 16 + kq * 4 + j;
          const float gv = tanhf(acc2[f][0][j] + (float)pg[f][j]);
          const float hn = z0reg[ii] * h0reg[ii] + (1.f - z0reg[ii]) * gv;
          h0reg[ii] = hn;
          st2_llc(P.h0seq + (size_t)(t + 1) * HB + (size_t)m * 1024 + c0 + r, (bf16)hn);
        }
      group_bar(flags0, rel0, 64, w, mast, 2 * t + 2);  // rel0=2(t+1): h0seq[t+1] ready
    }
#pragma unroll
    for (int f = 0; f < 2; ++f)
#pragma unroll
      for (int j = 0; j < 4; ++j) {
        const int m = m0w + f * 16 + kq * 4 + j;
        hid[(size_t)m * 2048 + c0 + r] = h0reg[f * 4 + j];
      }
  } else {
    // =================== L1 + OUT chain ===================
    const int lw = w - 64;  // 0..191
    const bool mast = (w == 64);
    float h1reg[4] = {}, z1reg[4] = {};
    float bz = 0.f, bg = 0.f, br = 0.f, byv = 0.f;
    if (role == 1) {
      bz = P.bh[3 * 1024 + c0 + r];
      bg = P.bh[5 * 1024 + c0 + r];
    } else {
      br = P.bh[4 * 1024 + c0 + r];
      byv = P.by[c0 + r];
    }
    for (int t = 0; t < 512; ++t) {
      // gate on L0 progress: h0seq[t+1] ready when rel0 >= 2(t+1)
      if (tid == 0) {
        while (__hip_atomic_load(rel0, __ATOMIC_RELAXED, __HIP_MEMORY_SCOPE_AGENT) <
               2 * (t + 1))
          __builtin_amdgcn_s_sleep(1);
      }
      __syncthreads();
      asm volatile("" ::: "memory");
      const bf16* x1 = P.h0seq + (size_t)(t + 1) * HB;   // L0 output at time t
      const bf16* h1p = P.h1seq + (size_t)t * HB;        // h1[t-1]
      bf16* rh1t = P.rh1seq + (P.sc_rh ? (size_t)(t & 1) : (size_t)t) * HB;

      // ---- phase A ----
      if (role == 1) {  // z1
        f32x4 acc[1][1] = {};
        mmA<1, 1, 4096>(x1, lds, 0, acc, m0z, r, kq);
        mmA<1, 1, 4096>(h1p, lds, 1024, acc, m0z, r, kq);
#pragma unroll
        for (int j = 0; j < 4; ++j) z1reg[j] = sigmf(acc[0][0][j] + bz);
      } else {  // r1 -> rh1
        float hp[2][4];
#pragma unroll
        for (int f = 0; f < 2; ++f)
#pragma unroll
          for (int j = 0; j < 4; ++j)
            hp[f][j] = (float)h1p[(size_t)(m0w + f * 16 + kq * 4 + j) * 1024 + c0 + r];
        f32x4 acc[2][1] = {};
        mmA<2, 1, 4096>(x1, lds, 0, acc, m0w, r, kq);
        mmA<2, 1, 4096>(h1p, lds, 1024, acc, m0w, r, kq);
#pragma unroll
        for (int f = 0; f < 2; ++f)
#pragma unroll
          for (int j = 0; j < 4; ++j) {
            const int m = m0w + f * 16 + kq * 4 + j;
            const float rv = sigmf(acc[f][0][j] + br);
            st2_llc(rh1t + (size_t)m * 1024 + c0 + r, (bf16)(rv * hp[f][j]));
          }
      }
      group_bar(flags1, rel1, 192, lw, mast, 2 * t + 1);

      // ---- phase B ----
      if (role == 1) {  // g1 + update
        f32x4 acc[1][1] = {};
        mmA<1, 1, 4096>(x1, lds + 65536, 0, acc, m0z, r, kq);
        if (P.sc_rh) mmA<1, 1, 4096, true>(rh1t, lds + 65536, 1024, acc, m0z, r, kq);
        else mmA<1, 1, 4096, false>(rh1t, lds + 65536, 1024, acc, m0z, r, kq);
#pragma unroll
        for (int j = 0; j < 4; ++j) {
          const int m = m0z + kq * 4 + j;
          const float gv = tanhf(acc[0][0][j] + bg);
          const float hn = z1reg[j] * h1reg[j] + (1.f - z1reg[j]) * gv;
          h1reg[j] = hn;
          st2_llc(P.h1seq + (size_t)(t + 1) * HB + (size_t)m * 1024 + c0 + r, (bf16)hn);
        }
      } else {  // OUT: y[t-1] = h1seq[t] @ Why^T + by
        if (t >= 1) {
          f32x4 acc[2][1] = {};
          mmA<2, 1, 2048>(h1p, lds + 65536, 0, acc, m0w, r, kq);
#pragma unroll
          for (int f = 0; f < 2; ++f)
#pragma unroll
            for (int j = 0; j < 4; ++j) {
              const int m = m0w + f * 16 + kq * 4 + j;
              P.out[((size_t)m * 512 + (t - 1)) * 1024 + c0 + r] = acc[f][0][j] + byv;
            }
        }
      }
      group_bar(flags1, rel1, 192, lw, mast, 2 * t + 2);
    }
    if (role == 1) {
#pragma unroll
      for (int j = 0; j < 4; ++j) {
        const int m = m0z + kq * 4 + j;
        hid[(size_t)m * 2048 + 1024 + c0 + r] = h1reg[j];
      }
    } else {  // tail: y[511] from h1seq[512]
      f32x4 acc[2][1] = {};
      mmA<2, 1, 2048>(P.h1seq + (size_t)512 * HB, lds + 65536, 0, acc, m0w, r, kq);
#pragma unroll
      for (int f = 0; f < 2; ++f)
#pragma unroll
        for (int j = 0; j < 4; ++j) {
          const int m = m0w + f * 16 + kq * 4 + j;
          P.out[((size_t)m * 512 + 511) * 1024 + c0 + r] = acc[f][0][j] + byv;
        }
    }
  }
}

extern "C" void kernel_launch(void* const* d_in, const int* in_sizes, int n_in,
                              void* d_out, int out_size, void* d_ws, size_t ws_size,
                              hipStream_t stream) {
  const float* x = (const float*)d_in[0];
  const float* Wx = (const float*)d_in[1];
  const float* Wh = (const float*)d_in[2];
  const float* bh = (const float*)d_in[3];
  const float* Why = (const float*)d_in[4];
  const float* by = (const float*)d_in[5];
  float* out = (float*)d_out;

  const size_t HBb = (size_t)131072 * 2;  // bytes per snapshot
  auto al = [](size_t x) { return (x + 255) & ~(size_t)255; };
  const size_t szWxb = al((size_t)3 * 1024 * 1024 * 2);
  const size_t szGx = al((size_t)512 * 3072 * 128 * 2);
  const size_t szHseq = al((size_t)513 * HBb);
  const size_t szRhFull = al((size_t)512 * HBb);
  const size_t szRhPar = al((size_t)2 * HBb);
  const size_t szBar = 32768;
  const size_t needFull = szWxb + szGx + 2 * szHseq + 2 * szRhFull + szBar;
  const int sc_rh = (ws_size >= needFull) ? 0 : 1;
  const size_t szRh = sc_rh ? szRhPar : szRhFull;

  char* ws = (char*)d_ws;
  size_t off = 0;
  auto alloc = [&](size_t bytes) -> void* {
    void* p = ws + off;
    off += bytes;
    return p;
  };
  bf16* Wxb = (bf16*)alloc(szWxb);
  bf16* gx0T = (bf16*)alloc(szGx);
  bf16* h0seq = (bf16*)alloc(szHseq);
  bf16* h1seq = (bf16*)alloc(szHseq);
  bf16* rh0seq = (bf16*)alloc(szRh);
  bf16* rh1seq = (bf16*)alloc(szRh);
  int* bar = (int*)alloc(szBar);

  hipFuncSetAttribute((const void*)k_gru, hipFuncAttributeMaxDynamicSharedMemorySize, 131072);

  k_cast4<<<512, 256, 0, stream>>>(Wx, Wxb, (3 * 1024 * 1024) / 4);
  hipMemsetAsync(h0seq, 0, 262144, stream);  // h0seq[0] = 0
  hipMemsetAsync(h1seq, 0, 262144, stream);  // h1seq[0] = 0
  hipMemsetAsync(bar, 0, szBar, stream);

  k_gx0T<<<12288, 256, 0, stream>>>(x, Wxb, bh, gx0T);

  GP gp{Wx, Wh, bh, by, Why, gx0T, h0seq, h1seq, rh0seq, rh1seq, out, bar, sc_rh};
  void* kargs[] = {&gp};
  hipLaunchCooperativeKernel((void*)k_gru, dim3(256), dim3(256), kargs, 131072, stream);
}